// Round 17
// baseline (151.702 us; speedup 1.0000x reference)
//
#include <hip/hip_runtime.h>

#define B_   2
#define CIN  128
#define H_   32
#define W_   48
#define HS   32
#define WS2  96
#define LT   3072
#define DI   256
#define NS   16
#define RK   8
#define KK   4
#define NCH  256
#define CHL  12   // NCH*CHL == LT

typedef unsigned int  u32;
typedef unsigned short u16;

__device__ __forceinline__ u16 f2bf(float x) {
  u32 u = __float_as_uint(x);
  return (u16)((u + 0x7FFFu + ((u >> 16) & 1u)) >> 16);
}
__device__ __forceinline__ float bf2f(u16 s) {
  return __uint_as_float((u32)s << 16);
}

// canonical token index for scan-order position ls of direction k
__device__ __forceinline__ int lcanon(int k, int ls) {
  if (k == 0) return ls;
  if (k == 1) return (ls & 31) * WS2 + (ls >> 5);
  if (k == 2) return LT - 1 - ls;
  int j = LT - 1 - ls;
  return (j & 31) * WS2 + (j >> 5);
}

// ---------------- kernel 0: weight transpose [512][128] -> [128][512] -------
__global__ __launch_bounds__(256) void k_wprep(
    const float* __restrict__ w, float* __restrict__ wT) {
  __shared__ float tile[32][33];
  int t = threadIdx.x;
  int bm = blockIdx.x & 15;    // m tile (512/32)
  int bk = blockIdx.x >> 4;    // k tile (128/32)
  int m0 = bm * 32, k0 = bk * 32;
  #pragma unroll
  for (int q = 0; q < 4; ++q) {
    int idx = q * 256 + t;
    int mi = idx >> 5, ki = idx & 31;
    tile[mi][ki] = w[(size_t)(m0 + mi) * CIN + k0 + ki];
  }
  __syncthreads();
  #pragma unroll
  for (int q = 0; q < 4; ++q) {
    int idx = q * 256 + t;
    int ki = idx >> 5, mi = idx & 31;
    wT[(size_t)(k0 + ki) * 512 + m0 + mi] = tile[mi][ki];
  }
}

// ------- kernel 1: token build + in_proj via wT, coalesced weight loads -----
// blocks [0,384): x-half (16 tok/tile); [384,576): z-half, ODD tokens only.
__global__ __launch_bounds__(256) void k_inproj(
    const float* __restrict__ rgb, const float* __restrict__ tin,
    const float* __restrict__ wT, float* __restrict__ xz) {
  __shared__ float xv[CIN][16];   // [c][tok]
  int t  = threadIdx.x;
  int bi = blockIdx.x;
  bool zh = bi >= 384;
  int bb, l0;
  if (!zh) { int r = bi;       bb = r / 192; l0 = (r % 192) * 16; }
  else     { int r = bi - 384; bb = r / 96;  l0 = (r % 96) * 32; }
  int h = l0 / WS2, w20 = l0 % WS2;
  #pragma unroll
  for (int rep = 0; rep < 8; ++rep) {
    int idx = rep * 256 + t;
    int tok = idx & 15, c = idx >> 4;
    int w2 = zh ? (w20 + 2 * tok + 1) : (w20 + tok);
    const float* src = (w2 & 1) ? tin : rgb;
    xv[c][tok] = src[((size_t)(bb * CIN + c) * HS + h) * W_ + (w2 >> 1)];
  }
  __syncthreads();
  int oc = (t & 63) * 4;          // oc within half [0,256)
  int th = t >> 6;                // token quad [0,4)
  const float4* wp = reinterpret_cast<const float4*>(wT + (zh ? 256 : 0) + oc);
  float4 A0 = {0,0,0,0}, A1 = {0,0,0,0}, A2 = {0,0,0,0}, A3 = {0,0,0,0};
  #pragma unroll 4
  for (int k = 0; k < CIN; ++k) {
    float4 w4 = wp[k * 128];      // 512 floats per k-row
    float4 x4 = *reinterpret_cast<const float4*>(&xv[k][th * 4]);
    A0.x += x4.x * w4.x; A0.y += x4.x * w4.y; A0.z += x4.x * w4.z; A0.w += x4.x * w4.w;
    A1.x += x4.y * w4.x; A1.y += x4.y * w4.y; A1.z += x4.y * w4.z; A1.w += x4.y * w4.w;
    A2.x += x4.z * w4.x; A2.y += x4.z * w4.y; A2.z += x4.z * w4.z; A2.w += x4.z * w4.w;
    A3.x += x4.w * w4.x; A3.y += x4.w * w4.y; A3.z += x4.w * w4.z; A3.w += x4.w * w4.w;
  }
  int colbase = (zh ? 256 : 0) + oc;
  #pragma unroll
  for (int j = 0; j < 4; ++j) {
    int tok = th * 4 + j;
    int l = zh ? (l0 + 2 * tok + 1) : (l0 + tok);
    float4 v = (j == 0) ? A0 : (j == 1) ? A1 : (j == 2) ? A2 : A3;
    *reinterpret_cast<float4*>(xz + ((size_t)bb * LT + l) * 512 + colbase) = v;
  }
}

// ---- kernel 2: FUSED depthwise conv+SiLU -> LDS -> x_proj/dt/B/C ----------
__global__ __launch_bounds__(256) void k_convdbc(
    const float* __restrict__ xz, const float* __restrict__ cw,
    const float* __restrict__ cbias, const float* __restrict__ xpw,
    float* __restrict__ xc, float* __restrict__ xcT,
    float* __restrict__ dts_sc, float* __restrict__ Bsb, float* __restrict__ Csb) {
  __shared__ float xv[8][260];        // [tok][d]
  __shared__ float outs2[128][9];     // B/C staging: row = k*32 + (c40-8)
  __shared__ float dts_s[KK][8][9];
  int t  = threadIdx.x;
  int bi = blockIdx.x;                // bb(2) * h(32) * q(12)
  int bb = bi / 384;
  int r  = bi % 384;
  int h  = r / 12;
  int q  = r % 12;
  int w0 = q * 8;
  int l0 = h * WS2 + w0;
  // ---- conv phase ----
  {
    float wreg[9];
    #pragma unroll
    for (int i = 0; i < 9; ++i) wreg[i] = cw[t * 9 + i];
    float bias = cbias[t];
    bool hm = (h > 0), hp = (h < HS - 1);
    const size_t rowb = ((size_t)bb * LT + h * WS2) * 512 + t;
    const size_t up = (size_t)WS2 * 512;
    float a0=0,a1=0,b0=0,b1=0,c0=0,c1=0;
    if (w0 > 0) {
      size_t o = rowb + (size_t)(w0 - 1) * 512;
      b0 = xz[o];
      if (hm) a0 = xz[o - up];
      if (hp) c0 = xz[o + up];
    }
    {
      size_t o = rowb + (size_t)w0 * 512;
      b1 = xz[o];
      if (hm) a1 = xz[o - up];
      if (hp) c1 = xz[o + up];
    }
    #pragma unroll
    for (int s = 0; s < 8; ++s) {
      int w2 = w0 + s;
      float a2 = 0, b2 = 0, c2 = 0;
      if (w2 + 1 < WS2) {
        size_t o = rowb + (size_t)(w2 + 1) * 512;
        b2 = xz[o];
        if (hm) a2 = xz[o - up];
        if (hp) c2 = xz[o + up];
      }
      float acc = bias
        + wreg[0]*a0 + wreg[1]*a1 + wreg[2]*a2
        + wreg[3]*b0 + wreg[4]*b1 + wreg[5]*b2
        + wreg[6]*c0 + wreg[7]*c1 + wreg[8]*c2;
      float sv = acc / (1.f + __expf(-acc));
      xc [((size_t)bb * LT + h * WS2 + w2) * DI + t] = sv;
      xcT[((size_t)bb * LT + w2 * 32 + h) * DI + t] = sv;   // WH-order stream
      xv[s][t] = sv;
      a0=a1; a1=a2; b0=b1; b1=b2; c0=c1; c1=c2;
    }
  }
  __syncthreads();
  // ---- x_proj phase (all 4 dirs, 160 channels) ----
  int i = t & 7, cb = t >> 3;          // token, channel base [0,32)
  float acc[5] = {0.f, 0.f, 0.f, 0.f, 0.f};
  const float4* xr  = reinterpret_cast<const float4*>(&xv[i][0]);
  const float4* wp0 = reinterpret_cast<const float4*>(xpw + (size_t)cb * DI);
  #pragma unroll 8
  for (int d4 = 0; d4 < 64; ++d4) {
    float4 x4 = xr[d4];
    #pragma unroll
    for (int j = 0; j < 5; ++j) {
      float4 w = wp0[j * 2048 + d4];   // row cb+32j
      acc[j] += w.x*x4.x + w.y*x4.y + w.z*x4.z + w.w*x4.w;
    }
  }
  #pragma unroll
  for (int j = 0; j < 5; ++j) {
    int cc  = cb + 32 * j;
    int k   = (cc * 205) >> 13;        // cc / 40
    int c40 = cc - 40 * k;
    if (c40 < RK) dts_s[k][i][c40] = acc[j];
    else          outs2[k * 32 + (c40 - RK)][i] = acc[j];
  }
  __syncthreads();
  // coalesced B/C writeout
  {
    int n = t & 15, tok = (t >> 4) & 7;
    bool isC = (t >= 128);
    int lc = l0 + tok, hh = h, w2 = w0 + tok;
    int lw = w2 * 32 + hh;
    int lsA[4] = {lc, lw, LT - 1 - lc, LT - 1 - lw};
    float* dst = isC ? Csb : Bsb;
    int off = isC ? 16 : 0;
    #pragma unroll
    for (int k = 0; k < KK; ++k)
      dst[(((size_t)bb * KK + k) * LT + lsA[k]) * NS + n] = outs2[k * 32 + off + n][tok];
  }
  // dts writeout (32B granules, scan order)
  {
    int k2 = t >> 6, tok2 = (t >> 3) & 7, rr = t & 7;
    int lc2 = l0 + tok2;
    int lw2 = (w0 + tok2) * 32 + h;
    int ls2 = (k2 == 0) ? lc2 : (k2 == 1) ? lw2 : (k2 == 2) ? (LT - 1 - lc2) : (LT - 1 - lw2);
    dts_sc[(((size_t)bb * KK + k2) * LT + ls2) * RK + rr] = dts_s[k2][tok2][rr];
  }
}

// ---------------- kernel 4: scan phase 1 (per-chunk local state) ------------
// Chunk-uniform streams (dts, B) staged in LDS; u prefetched; 6 waves/SIMD.
__global__ __launch_bounds__(256, 6) void k_scan1(
    const float* __restrict__ dts_sc, const float* __restrict__ xc,
    const float* __restrict__ xcT, const float* __restrict__ Bsb,
    const float* __restrict__ dtw, const float* __restrict__ dtb,
    const float* __restrict__ Alog, u16* __restrict__ chH,
    float* __restrict__ sumd) {
  __shared__ float ldsD[CHL * RK];   // 96 floats
  __shared__ float ldsB[CHL * NS];   // 192 floats
  int t  = threadIdx.x;
  int bi = blockIdx.x;
  int bb = bi / (KK * NCH);
  int k  = (bi / NCH) % KK;
  int ch = bi % NCH;
  size_t bk = (size_t)bb * KK + k;
  {
    const float* dspan = dts_sc + (bk * LT + (size_t)ch * CHL) * RK;  // 96 f
    const float* bspan = Bsb + (bk * LT + (size_t)ch * CHL) * NS;     // 192 f
    if (t < CHL * RK) ldsD[t] = dspan[t];
    if (t < CHL * NS) ldsB[t] = bspan[t];
  }
  const float* src = ((k & 1) ? xcT : xc) + (size_t)bb * LT * DI;
  int dir = (k < 2) ? 1 : -1;
  int i0  = (k < 2) ? ch * CHL : LT - 1 - ch * CHL;
  const float* wr = dtw + ((size_t)k * DI + t) * RK;
  float4 w0 = *reinterpret_cast<const float4*>(wr);
  float4 w1 = *reinterpret_cast<const float4*>(wr + 4);
  float bias = dtb[k * DI + t];
  const float* arow = Alog + ((size_t)k * DI + t) * NS;
  float a0 = -__expf(arow[0]);
  bool okf = true;
  for (int n = 1; n < NS; ++n) {
    float an = -__expf(arow[n]);
    okf = okf && (fabsf(an - (n + 1) * a0) <= 1e-3f * (n + 1) * fabsf(a0));
  }
  float h[NS];
  #pragma unroll
  for (int n = 0; n < NS; ++n) h[n] = 0.f;
  float sd = 0.f;
  float u_nxt = src[(size_t)i0 * DI + t];
  __syncthreads();
  if (okf) {
    for (int s = 0; s < CHL; ++s) {
      float u = u_nxt;
      int sn = (s + 1 < CHL) ? s + 1 : s;
      u_nxt = src[(size_t)(i0 + dir * sn) * DI + t];
      const float4* qd = reinterpret_cast<const float4*>(&ldsD[s * RK]);
      float4 q0 = qd[0], q1 = qd[1];
      const float4* bd = reinterpret_cast<const float4*>(&ldsB[s * NS]);
      float4 b0 = bd[0], b1 = bd[1], b2 = bd[2], b3 = bd[3];
      float xx = bias + w0.x*q0.x + w0.y*q0.y + w0.z*q0.z + w0.w*q0.w
                      + w1.x*q1.x + w1.y*q1.y + w1.z*q1.z + w1.w*q1.w;
      float dlt = fmaxf(xx, 0.f) + __logf(1.f + __expf(-fabsf(xx)));
      sd += dlt;
      float du = dlt * u;
      float e1 = __expf(dlt * a0);
      float bv[16] = {b0.x,b0.y,b0.z,b0.w, b1.x,b1.y,b1.z,b1.w,
                      b2.x,b2.y,b2.z,b2.w, b3.x,b3.y,b3.z,b3.w};
      float p = e1;
      #pragma unroll
      for (int n = 0; n < NS; ++n) { h[n] = p * h[n] + du * bv[n]; p *= e1; }
    }
  } else {
    float a[NS];
    #pragma unroll
    for (int n = 0; n < NS; ++n) a[n] = -__expf(arow[n]);
    for (int s = 0; s < CHL; ++s) {
      float u = u_nxt;
      int sn = (s + 1 < CHL) ? s + 1 : s;
      u_nxt = src[(size_t)(i0 + dir * sn) * DI + t];
      const float4* qd = reinterpret_cast<const float4*>(&ldsD[s * RK]);
      float4 q0 = qd[0], q1 = qd[1];
      const float4* bd = reinterpret_cast<const float4*>(&ldsB[s * NS]);
      float4 b0 = bd[0], b1 = bd[1], b2 = bd[2], b3 = bd[3];
      float xx = bias + w0.x*q0.x + w0.y*q0.y + w0.z*q0.z + w0.w*q0.w
                      + w1.x*q1.x + w1.y*q1.y + w1.z*q1.z + w1.w*q1.w;
      float dlt = fmaxf(xx, 0.f) + __logf(1.f + __expf(-fabsf(xx)));
      sd += dlt;
      float du = dlt * u;
      float bv[16] = {b0.x,b0.y,b0.z,b0.w, b1.x,b1.y,b1.z,b1.w,
                      b2.x,b2.y,b2.z,b2.w, b3.x,b3.y,b3.z,b3.w};
      #pragma unroll
      for (int n = 0; n < NS; ++n) h[n] = __expf(dlt * a[n]) * h[n] + du * bv[n];
    }
  }
  u32 pk[8];
  #pragma unroll
  for (int i = 0; i < 8; ++i)
    pk[i] = (u32)f2bf(h[2*i]) | ((u32)f2bf(h[2*i+1]) << 16);
  u32* outp = reinterpret_cast<u32*>(chH + ((bk * NCH + ch) * DI + t) * NS);
  *reinterpret_cast<uint4*>(outp)     = make_uint4(pk[0], pk[1], pk[2], pk[3]);
  *reinterpret_cast<uint4*>(outp + 4) = make_uint4(pk[4], pk[5], pk[6], pk[7]);
  sumd[(bk * NCH + ch) * DI + t] = sd;
}

// ------- kernel 5: carry across chunks, IN-PLACE (chH becomes h_in) ---------
__global__ __launch_bounds__(256) void k_scan2(
    u16* __restrict__ chH, const float* __restrict__ sumd,
    const float* __restrict__ Alog) {
  int t  = threadIdx.x;
  int bi = blockIdx.x;
  int bb = bi / (KK * 16);
  int k  = (bi / 16) % KK;
  int dg = bi % 16;
  int d = dg * 16 + (t >> 4);
  int n = t & 15;
  float a = -__expf(Alog[((size_t)k * DI + d) * NS + n]);
  float carry = 0.f;
  size_t bk = (size_t)bb * KK + k;
  size_t base = (bk * NCH) * DI + d;
  float Hc = bf2f(chH[base * NS + n]);
  float sd = sumd[base];
  for (int ch = 0; ch < NCH; ++ch) {
    size_t nbase = base + DI;
    float Hc2 = 0.f, sd2 = 0.f;
    if (ch + 1 < NCH) { Hc2 = bf2f(chH[nbase * NS + n]); sd2 = sumd[nbase]; }
    chH[base * NS + n] = f2bf(carry);
    carry = __expf(a * sd) * carry + Hc;
    base = nbase; Hc = Hc2; sd = sd2;
  }
}

// ------- kernel 6: scan phase 3 (re-scan with carry, emit y odd-only) -------
// Chunk-uniform streams (dts, B, C) staged in LDS; u prefetched; 6 waves/SIMD.
__global__ __launch_bounds__(256, 6) void k_scan3(
    const float* __restrict__ dts_sc, const float* __restrict__ xc,
    const float* __restrict__ xcT, const float* __restrict__ Bsb,
    const float* __restrict__ Csb, const float* __restrict__ dtw,
    const float* __restrict__ dtb, const float* __restrict__ Alog,
    const float* __restrict__ Ds, const u16* __restrict__ chH,
    u16* __restrict__ yhalf) {
  __shared__ float ldsD[CHL * RK];   // 96
  __shared__ float ldsB[CHL * NS];   // 192
  __shared__ float ldsC[CHL * NS];   // 192
  int t  = threadIdx.x;
  int bi = blockIdx.x;
  int bb = bi / (KK * NCH);
  int k  = (bi / NCH) % KK;
  int ch = bi % NCH;
  size_t bk = (size_t)bb * KK + k;
  {
    const float* dspan = dts_sc + (bk * LT + (size_t)ch * CHL) * RK;
    const float* bspan = Bsb + (bk * LT + (size_t)ch * CHL) * NS;
    const float* cspan = Csb + (bk * LT + (size_t)ch * CHL) * NS;
    if (t < CHL * RK) ldsD[t] = dspan[t];
    if (t < CHL * NS) { ldsB[t] = bspan[t]; ldsC[t] = cspan[t]; }
  }
  const float* src = ((k & 1) ? xcT : xc) + (size_t)bb * LT * DI;
  int dir = (k < 2) ? 1 : -1;
  int i0  = (k < 2) ? ch * CHL : LT - 1 - ch * CHL;
  const float* wr = dtw + ((size_t)k * DI + t) * RK;
  float4 w0 = *reinterpret_cast<const float4*>(wr);
  float4 w1 = *reinterpret_cast<const float4*>(wr + 4);
  float bias = dtb[k * DI + t];
  const float* arow = Alog + ((size_t)k * DI + t) * NS;
  float a0 = -__expf(arow[0]);
  bool okf = true;
  for (int n = 1; n < NS; ++n) {
    float an = -__expf(arow[n]);
    okf = okf && (fabsf(an - (n + 1) * a0) <= 1e-3f * (n + 1) * fabsf(a0));
  }
  float h[NS];
  {
    const uint4* hp4 = reinterpret_cast<const uint4*>(chH + ((bk * NCH + ch) * DI + t) * NS);
    uint4 A = hp4[0], Bq = hp4[1];
    u32 w[8] = {A.x, A.y, A.z, A.w, Bq.x, Bq.y, Bq.z, Bq.w};
    #pragma unroll
    for (int i = 0; i < 8; ++i) {
      h[2*i]   = bf2f((u16)(w[i] & 0xFFFFu));
      h[2*i+1] = bf2f((u16)(w[i] >> 16));
    }
  }
  float dv = Ds[k * DI + t];
  float u_nxt = src[(size_t)i0 * DI + t];
  __syncthreads();
  if (okf) {
    for (int s = 0; s < CHL; ++s) {
      float u = u_nxt;
      int sn = (s + 1 < CHL) ? s + 1 : s;
      u_nxt = src[(size_t)(i0 + dir * sn) * DI + t];
      const float4* qd = reinterpret_cast<const float4*>(&ldsD[s * RK]);
      float4 q0 = qd[0], q1 = qd[1];
      const float4* bd = reinterpret_cast<const float4*>(&ldsB[s * NS]);
      float4 b0 = bd[0], b1 = bd[1], b2 = bd[2], b3 = bd[3];
      const float4* cd = reinterpret_cast<const float4*>(&ldsC[s * NS]);
      float4 c0 = cd[0], c1 = cd[1], c2 = cd[2], c3 = cd[3];
      float xx = bias + w0.x*q0.x + w0.y*q0.y + w0.z*q0.z + w0.w*q0.w
                      + w1.x*q1.x + w1.y*q1.y + w1.z*q1.z + w1.w*q1.w;
      float dlt = fmaxf(xx, 0.f) + __logf(1.f + __expf(-fabsf(xx)));
      float du = dlt * u;
      float e1 = __expf(dlt * a0);
      float bv[16] = {b0.x,b0.y,b0.z,b0.w, b1.x,b1.y,b1.z,b1.w,
                      b2.x,b2.y,b2.z,b2.w, b3.x,b3.y,b3.z,b3.w};
      float cv[16] = {c0.x,c0.y,c0.z,c0.w, c1.x,c1.y,c1.z,c1.w,
                      c2.x,c2.y,c2.z,c2.w, c3.x,c3.y,c3.z,c3.w};
      float p = e1;
      float y = 0.f;
      #pragma unroll
      for (int n = 0; n < NS; ++n) { h[n] = p * h[n] + du * bv[n]; y += h[n] * cv[n]; p *= e1; }
      y += dv * u;
      int ls = ch * CHL + s;
      int lc = lcanon(k, ls);
      if (lc & 1)
        yhalf[(bk * (LT/2) + (lc >> 1)) * DI + t] = f2bf(y);
    }
  } else {
    float a[NS];
    #pragma unroll
    for (int n = 0; n < NS; ++n) a[n] = -__expf(arow[n]);
    for (int s = 0; s < CHL; ++s) {
      float u = u_nxt;
      int sn = (s + 1 < CHL) ? s + 1 : s;
      u_nxt = src[(size_t)(i0 + dir * sn) * DI + t];
      const float4* qd = reinterpret_cast<const float4*>(&ldsD[s * RK]);
      float4 q0 = qd[0], q1 = qd[1];
      const float4* bd = reinterpret_cast<const float4*>(&ldsB[s * NS]);
      float4 b0 = bd[0], b1 = bd[1], b2 = bd[2], b3 = bd[3];
      const float4* cd = reinterpret_cast<const float4*>(&ldsC[s * NS]);
      float4 c0 = cd[0], c1 = cd[1], c2 = cd[2], c3 = cd[3];
      float xx = bias + w0.x*q0.x + w0.y*q0.y + w0.z*q0.z + w0.w*q0.w
                      + w1.x*q1.x + w1.y*q1.y + w1.z*q1.z + w1.w*q1.w;
      float dlt = fmaxf(xx, 0.f) + __logf(1.f + __expf(-fabsf(xx)));
      float du = dlt * u;
      float bv[16] = {b0.x,b0.y,b0.z,b0.w, b1.x,b1.y,b1.z,b1.w,
                      b2.x,b2.y,b2.z,b2.w, b3.x,b3.y,b3.z,b3.w};
      float cv[16] = {c0.x,c0.y,c0.z,c0.w, c1.x,c1.y,c1.z,c1.w,
                      c2.x,c2.y,c2.z,c2.w, c3.x,c3.y,c3.z,c3.w};
      float y = 0.f;
      #pragma unroll
      for (int n = 0; n < NS; ++n) { h[n] = __expf(dlt * a[n]) * h[n] + du * bv[n]; y += h[n] * cv[n]; }
      y += dv * u;
      int ls = ch * CHL + s;
      int lc = lcanon(k, ls);
      if (lc & 1)
        yhalf[(bk * (LT/2) + (lc >> 1)) * DI + t] = f2bf(y);
    }
  }
}

// ---------------- kernel 7: merge + LN + gate + out_proj (4 tok/block) ------
__global__ __launch_bounds__(256) void k_out(
    const u16* __restrict__ yhalf, const float* __restrict__ xz,
    const float* __restrict__ gam, const float* __restrict__ be,
    const float* __restrict__ opw, float* __restrict__ out) {
  __shared__ float yt[4][260];
  int t = threadIdx.x;
  int bb   = blockIdx.x / 384;
  int tile = blockIdx.x % 384;
  {
    int lane = t & 63, tok = t >> 6;
    int m = tile * 4 + tok;               // odd-token index within batch
    int lc = (m / W_) * WS2 + (m % W_) * 2 + 1;
    float yv[4];
    #pragma unroll
    for (int j = 0; j < 4; ++j) {
      int d = lane + 64 * j;
      float s = 0.f;
      #pragma unroll
      for (int k = 0; k < KK; ++k)
        s += bf2f(yhalf[(((size_t)bb * KK + k) * (LT/2) + m) * DI + d]);
      yv[j] = s;
    }
    float sum = yv[0] + yv[1] + yv[2] + yv[3];
    #pragma unroll
    for (int off = 32; off > 0; off >>= 1) sum += __shfl_xor(sum, off, 64);
    float mu = sum * (1.f / DI);
    float sq = 0.f;
    #pragma unroll
    for (int j = 0; j < 4; ++j) { float dd = yv[j] - mu; sq += dd * dd; }
    #pragma unroll
    for (int off = 32; off > 0; off >>= 1) sq += __shfl_xor(sq, off, 64);
    float rs = rsqrtf(sq * (1.f / DI) + 1e-5f);
    #pragma unroll
    for (int j = 0; j < 4; ++j) {
      int d = lane + 64 * j;
      float z = xz[((size_t)bb * LT + lc) * 512 + DI + d];
      float sz = z / (1.f + __expf(-z));
      yt[tok][d] = ((yv[j] - mu) * rs * gam[d] + be[d]) * sz;
    }
  }
  __syncthreads();
  int i = t & 3, og = t >> 2;              // token, oc in [0,64)
  const float4* yr = reinterpret_cast<const float4*>(&yt[i][0]);
  const float4* w0p = reinterpret_cast<const float4*>(opw + (size_t)og * DI);
  const float4* w1p = reinterpret_cast<const float4*>(opw + (size_t)(og + 64) * DI);
  float a0 = 0.f, a1 = 0.f;
  for (int d4 = 0; d4 < 64; ++d4) {
    float4 y4 = yr[d4];
    float4 wa = w0p[d4], wb2 = w1p[d4];
    a0 += wa.x*y4.x + wa.y*y4.y + wa.z*y4.z + wa.w*y4.w;
    a1 += wb2.x*y4.x + wb2.y*y4.y + wb2.z*y4.z + wb2.w*y4.w;
  }
  int m = tile * 4 + i;
  int hh = m / W_, ww = m % W_;
  out[((size_t)(bb * CIN + og) * HS + hh) * W_ + ww] = a0;
  out[((size_t)(bb * CIN + og + 64) * HS + hh) * W_ + ww] = a1;
}

extern "C" void kernel_launch(void* const* d_in, const int* in_sizes, int n_in,
                              void* d_out, int out_size, void* d_ws, size_t ws_size,
                              hipStream_t stream) {
  const float* rgb  = (const float*)d_in[0];
  const float* tin  = (const float*)d_in[1];
  const float* ipw  = (const float*)d_in[2];
  const float* cw   = (const float*)d_in[3];
  const float* cb   = (const float*)d_in[4];
  const float* xpw  = (const float*)d_in[5];
  const float* dtw  = (const float*)d_in[6];
  const float* dtb  = (const float*)d_in[7];
  const float* Alog = (const float*)d_in[8];
  const float* Ds   = (const float*)d_in[9];
  const float* g    = (const float*)d_in[10];
  const float* be   = (const float*)d_in[11];
  const float* opw  = (const float*)d_in[12];
  float* out = (float*)d_out;

  // f-slot layout (verified, NCH=256): end = 13,631,488 floats (~54.5 MB)
  float* ws    = (float*)d_ws;
  float* xz    = ws;                        // 3,145,728 f
  float* xc    = ws + 3145728;              // 1,572,864 f
  float* xcT   = ws + 4718592;              // 1,572,864 f
  float* dts   = ws + 6291456;              //   196,608 f
  float* Bsb   = ws + 6488064;              //   393,216 f
  float* Csb   = ws + 6881280;              //   393,216 f
  u16*   chH   = (u16*)(ws + 7274496);      // 8,388,608 bf16 = 4,194,304 f
  float* sumd  = ws + 11468800;             //   524,288 f
  u16*   yhalf = (u16*)(ws + 11993088);     // 3,145,728 bf16 = 1,572,864 f
  float* wT    = ws + 13565952;             //    65,536 f

  k_wprep  <<<64,   256, 0, stream>>>(ipw, wT);
  k_inproj <<<576,  256, 0, stream>>>(rgb, tin, wT, xz);
  k_convdbc<<<768,  256, 0, stream>>>(xz, cw, cb, xpw, xc, xcT, dts, Bsb, Csb);
  k_scan1  <<<2048, 256, 0, stream>>>(dts, xc, xcT, Bsb, dtw, dtb, Alog, chH, sumd);
  k_scan2  <<<128,  256, 0, stream>>>(chH, sumd, Alog);
  k_scan3  <<<2048, 256, 0, stream>>>(dts, xc, xcT, Bsb, Csb, dtw, dtb, Alog, Ds, chH, yhalf);
  k_out    <<<768,  256, 0, stream>>>(yhalf, xz, g, be, opw, out);
}

// Round 18
// 150.452 us; speedup vs baseline: 1.0083x; 1.0083x over previous
//
#include <hip/hip_runtime.h>

#define B_   2
#define CIN  128
#define H_   32
#define W_   48
#define HS   32
#define WS2  96
#define LT   3072
#define DI   256
#define NS   16
#define RK   8
#define KK   4
#define NCH  192
#define CHL  16   // NCH*CHL == LT

typedef unsigned int  u32;
typedef unsigned short u16;

__device__ __forceinline__ u16 f2bf(float x) {
  u32 u = __float_as_uint(x);
  return (u16)((u + 0x7FFFu + ((u >> 16) & 1u)) >> 16);
}
__device__ __forceinline__ float bf2f(u16 s) {
  return __uint_as_float((u32)s << 16);
}

// canonical token index for scan-order position ls of direction k
__device__ __forceinline__ int lcanon(int k, int ls) {
  if (k == 0) return ls;
  if (k == 1) return (ls & 31) * WS2 + (ls >> 5);
  if (k == 2) return LT - 1 - ls;
  int j = LT - 1 - ls;
  return (j & 31) * WS2 + (j >> 5);
}

// ---------------- kernel 0: weight transpose [512][128] -> [128][512] -------
__global__ __launch_bounds__(256) void k_wprep(
    const float* __restrict__ w, float* __restrict__ wT) {
  __shared__ float tile[32][33];
  int t = threadIdx.x;
  int bm = blockIdx.x & 15;    // m tile (512/32)
  int bk = blockIdx.x >> 4;    // k tile (128/32)
  int m0 = bm * 32, k0 = bk * 32;
  #pragma unroll
  for (int q = 0; q < 4; ++q) {
    int idx = q * 256 + t;
    int mi = idx >> 5, ki = idx & 31;
    tile[mi][ki] = w[(size_t)(m0 + mi) * CIN + k0 + ki];
  }
  __syncthreads();
  #pragma unroll
  for (int q = 0; q < 4; ++q) {
    int idx = q * 256 + t;
    int ki = idx >> 5, mi = idx & 31;
    wT[(size_t)(k0 + ki) * 512 + m0 + mi] = tile[mi][ki];
  }
}

// ------- kernel 1: token build + in_proj via wT, coalesced weight loads -----
// blocks [0,384): x-half (16 tok/tile); [384,576): z-half, ODD tokens only.
__global__ __launch_bounds__(256) void k_inproj(
    const float* __restrict__ rgb, const float* __restrict__ tin,
    const float* __restrict__ wT, float* __restrict__ xz) {
  __shared__ float xv[CIN][16];   // [c][tok]
  int t  = threadIdx.x;
  int bi = blockIdx.x;
  bool zh = bi >= 384;
  int bb, l0;
  if (!zh) { int r = bi;       bb = r / 192; l0 = (r % 192) * 16; }
  else     { int r = bi - 384; bb = r / 96;  l0 = (r % 96) * 32; }
  int h = l0 / WS2, w20 = l0 % WS2;
  #pragma unroll
  for (int rep = 0; rep < 8; ++rep) {
    int idx = rep * 256 + t;
    int tok = idx & 15, c = idx >> 4;
    int w2 = zh ? (w20 + 2 * tok + 1) : (w20 + tok);
    const float* src = (w2 & 1) ? tin : rgb;
    xv[c][tok] = src[((size_t)(bb * CIN + c) * HS + h) * W_ + (w2 >> 1)];
  }
  __syncthreads();
  int oc = (t & 63) * 4;          // oc within half [0,256)
  int th = t >> 6;                // token quad [0,4)
  const float4* wp = reinterpret_cast<const float4*>(wT + (zh ? 256 : 0) + oc);
  float4 A0 = {0,0,0,0}, A1 = {0,0,0,0}, A2 = {0,0,0,0}, A3 = {0,0,0,0};
  #pragma unroll 4
  for (int k = 0; k < CIN; ++k) {
    float4 w4 = wp[k * 128];      // 512 floats per k-row
    float4 x4 = *reinterpret_cast<const float4*>(&xv[k][th * 4]);
    A0.x += x4.x * w4.x; A0.y += x4.x * w4.y; A0.z += x4.x * w4.z; A0.w += x4.x * w4.w;
    A1.x += x4.y * w4.x; A1.y += x4.y * w4.y; A1.z += x4.y * w4.z; A1.w += x4.y * w4.w;
    A2.x += x4.z * w4.x; A2.y += x4.z * w4.y; A2.z += x4.z * w4.z; A2.w += x4.z * w4.w;
    A3.x += x4.w * w4.x; A3.y += x4.w * w4.y; A3.z += x4.w * w4.z; A3.w += x4.w * w4.w;
  }
  int colbase = (zh ? 256 : 0) + oc;
  #pragma unroll
  for (int j = 0; j < 4; ++j) {
    int tok = th * 4 + j;
    int l = zh ? (l0 + 2 * tok + 1) : (l0 + tok);
    float4 v = (j == 0) ? A0 : (j == 1) ? A1 : (j == 2) ? A2 : A3;
    *reinterpret_cast<float4*>(xz + ((size_t)bb * LT + l) * 512 + colbase) = v;
  }
}

// ---- kernel 2: FUSED depthwise conv+SiLU -> LDS -> x_proj/dt/B/C ----------
__global__ __launch_bounds__(256) void k_convdbc(
    const float* __restrict__ xz, const float* __restrict__ cw,
    const float* __restrict__ cbias, const float* __restrict__ xpw,
    float* __restrict__ xc, float* __restrict__ xcT,
    float* __restrict__ dts_sc, float* __restrict__ Bsb, float* __restrict__ Csb) {
  __shared__ float xv[8][260];        // [tok][d]
  __shared__ float outs2[128][9];     // B/C staging: row = k*32 + (c40-8)
  __shared__ float dts_s[KK][8][9];
  int t  = threadIdx.x;
  int bi = blockIdx.x;                // bb(2) * h(32) * q(12)
  int bb = bi / 384;
  int r  = bi % 384;
  int h  = r / 12;
  int q  = r % 12;
  int w0 = q * 8;
  int l0 = h * WS2 + w0;
  // ---- conv phase ----
  {
    float wreg[9];
    #pragma unroll
    for (int i = 0; i < 9; ++i) wreg[i] = cw[t * 9 + i];
    float bias = cbias[t];
    bool hm = (h > 0), hp = (h < HS - 1);
    const size_t rowb = ((size_t)bb * LT + h * WS2) * 512 + t;
    const size_t up = (size_t)WS2 * 512;
    float a0=0,a1=0,b0=0,b1=0,c0=0,c1=0;
    if (w0 > 0) {
      size_t o = rowb + (size_t)(w0 - 1) * 512;
      b0 = xz[o];
      if (hm) a0 = xz[o - up];
      if (hp) c0 = xz[o + up];
    }
    {
      size_t o = rowb + (size_t)w0 * 512;
      b1 = xz[o];
      if (hm) a1 = xz[o - up];
      if (hp) c1 = xz[o + up];
    }
    #pragma unroll
    for (int s = 0; s < 8; ++s) {
      int w2 = w0 + s;
      float a2 = 0, b2 = 0, c2 = 0;
      if (w2 + 1 < WS2) {
        size_t o = rowb + (size_t)(w2 + 1) * 512;
        b2 = xz[o];
        if (hm) a2 = xz[o - up];
        if (hp) c2 = xz[o + up];
      }
      float acc = bias
        + wreg[0]*a0 + wreg[1]*a1 + wreg[2]*a2
        + wreg[3]*b0 + wreg[4]*b1 + wreg[5]*b2
        + wreg[6]*c0 + wreg[7]*c1 + wreg[8]*c2;
      float sv = acc / (1.f + __expf(-acc));
      xc [((size_t)bb * LT + h * WS2 + w2) * DI + t] = sv;
      xcT[((size_t)bb * LT + w2 * 32 + h) * DI + t] = sv;   // WH-order stream
      xv[s][t] = sv;
      a0=a1; a1=a2; b0=b1; b1=b2; c0=c1; c1=c2;
    }
  }
  __syncthreads();
  // ---- x_proj phase (all 4 dirs, 160 channels) ----
  int i = t & 7, cb = t >> 3;          // token, channel base [0,32)
  float acc[5] = {0.f, 0.f, 0.f, 0.f, 0.f};
  const float4* xr  = reinterpret_cast<const float4*>(&xv[i][0]);
  const float4* wp0 = reinterpret_cast<const float4*>(xpw + (size_t)cb * DI);
  #pragma unroll 8
  for (int d4 = 0; d4 < 64; ++d4) {
    float4 x4 = xr[d4];
    #pragma unroll
    for (int j = 0; j < 5; ++j) {
      float4 w = wp0[j * 2048 + d4];   // row cb+32j
      acc[j] += w.x*x4.x + w.y*x4.y + w.z*x4.z + w.w*x4.w;
    }
  }
  #pragma unroll
  for (int j = 0; j < 5; ++j) {
    int cc  = cb + 32 * j;
    int k   = (cc * 205) >> 13;        // cc / 40
    int c40 = cc - 40 * k;
    if (c40 < RK) dts_s[k][i][c40] = acc[j];
    else          outs2[k * 32 + (c40 - RK)][i] = acc[j];
  }
  __syncthreads();
  // coalesced B/C writeout
  {
    int n = t & 15, tok = (t >> 4) & 7;
    bool isC = (t >= 128);
    int lc = l0 + tok, hh = h, w2 = w0 + tok;
    int lw = w2 * 32 + hh;
    int lsA[4] = {lc, lw, LT - 1 - lc, LT - 1 - lw};
    float* dst = isC ? Csb : Bsb;
    int off = isC ? 16 : 0;
    #pragma unroll
    for (int k = 0; k < KK; ++k)
      dst[(((size_t)bb * KK + k) * LT + lsA[k]) * NS + n] = outs2[k * 32 + off + n][tok];
  }
  // dts writeout (32B granules, scan order)
  {
    int k2 = t >> 6, tok2 = (t >> 3) & 7, rr = t & 7;
    int lc2 = l0 + tok2;
    int lw2 = (w0 + tok2) * 32 + h;
    int ls2 = (k2 == 0) ? lc2 : (k2 == 1) ? lw2 : (k2 == 2) ? (LT - 1 - lc2) : (LT - 1 - lw2);
    dts_sc[(((size_t)bb * KK + k2) * LT + ls2) * RK + rr] = dts_s[k2][tok2][rr];
  }
}

// ---------------- kernel 4: scan phase 1 (per-chunk local state) ------------
// Chunk-uniform streams (dts, B) staged in LDS; u prefetched; 6 waves/SIMD.
__global__ __launch_bounds__(256, 6) void k_scan1(
    const float* __restrict__ dts_sc, const float* __restrict__ xc,
    const float* __restrict__ xcT, const float* __restrict__ Bsb,
    const float* __restrict__ dtw, const float* __restrict__ dtb,
    const float* __restrict__ Alog, u16* __restrict__ chH,
    float* __restrict__ sumd) {
  __shared__ float ldsD[CHL * RK];   // 128 floats
  __shared__ float ldsB[CHL * NS];   // 256 floats
  int t  = threadIdx.x;
  int bi = blockIdx.x;
  int bb = bi / (KK * NCH);
  int k  = (bi / NCH) % KK;
  int ch = bi % NCH;
  size_t bk = (size_t)bb * KK + k;
  {
    const float* dspan = dts_sc + (bk * LT + (size_t)ch * CHL) * RK;  // 128 f
    const float* bspan = Bsb + (bk * LT + (size_t)ch * CHL) * NS;     // 256 f
    if (t < CHL * RK) ldsD[t] = dspan[t];
    ldsB[t] = bspan[t];
  }
  const float* src = ((k & 1) ? xcT : xc) + (size_t)bb * LT * DI;
  int dir = (k < 2) ? 1 : -1;
  int i0  = (k < 2) ? ch * CHL : LT - 1 - ch * CHL;
  const float* wr = dtw + ((size_t)k * DI + t) * RK;
  float4 w0 = *reinterpret_cast<const float4*>(wr);
  float4 w1 = *reinterpret_cast<const float4*>(wr + 4);
  float bias = dtb[k * DI + t];
  const float* arow = Alog + ((size_t)k * DI + t) * NS;
  float a0 = -__expf(arow[0]);
  bool okf = true;
  for (int n = 1; n < NS; ++n) {
    float an = -__expf(arow[n]);
    okf = okf && (fabsf(an - (n + 1) * a0) <= 1e-3f * (n + 1) * fabsf(a0));
  }
  float h[NS];
  #pragma unroll
  for (int n = 0; n < NS; ++n) h[n] = 0.f;
  float sd = 0.f;
  float u_nxt = src[(size_t)i0 * DI + t];
  __syncthreads();
  if (okf) {
    for (int s = 0; s < CHL; ++s) {
      float u = u_nxt;
      int sn = (s + 1 < CHL) ? s + 1 : s;
      u_nxt = src[(size_t)(i0 + dir * sn) * DI + t];
      const float4* qd = reinterpret_cast<const float4*>(&ldsD[s * RK]);
      float4 q0 = qd[0], q1 = qd[1];
      const float4* bd = reinterpret_cast<const float4*>(&ldsB[s * NS]);
      float4 b0 = bd[0], b1 = bd[1], b2 = bd[2], b3 = bd[3];
      float xx = bias + w0.x*q0.x + w0.y*q0.y + w0.z*q0.z + w0.w*q0.w
                      + w1.x*q1.x + w1.y*q1.y + w1.z*q1.z + w1.w*q1.w;
      float dlt = fmaxf(xx, 0.f) + __logf(1.f + __expf(-fabsf(xx)));
      sd += dlt;
      float du = dlt * u;
      float e1 = __expf(dlt * a0);
      float bv[16] = {b0.x,b0.y,b0.z,b0.w, b1.x,b1.y,b1.z,b1.w,
                      b2.x,b2.y,b2.z,b2.w, b3.x,b3.y,b3.z,b3.w};
      float p = e1;
      #pragma unroll
      for (int n = 0; n < NS; ++n) { h[n] = p * h[n] + du * bv[n]; p *= e1; }
    }
  } else {
    float a[NS];
    #pragma unroll
    for (int n = 0; n < NS; ++n) a[n] = -__expf(arow[n]);
    for (int s = 0; s < CHL; ++s) {
      float u = u_nxt;
      int sn = (s + 1 < CHL) ? s + 1 : s;
      u_nxt = src[(size_t)(i0 + dir * sn) * DI + t];
      const float4* qd = reinterpret_cast<const float4*>(&ldsD[s * RK]);
      float4 q0 = qd[0], q1 = qd[1];
      const float4* bd = reinterpret_cast<const float4*>(&ldsB[s * NS]);
      float4 b0 = bd[0], b1 = bd[1], b2 = bd[2], b3 = bd[3];
      float xx = bias + w0.x*q0.x + w0.y*q0.y + w0.z*q0.z + w0.w*q0.w
                      + w1.x*q1.x + w1.y*q1.y + w1.z*q1.z + w1.w*q1.w;
      float dlt = fmaxf(xx, 0.f) + __logf(1.f + __expf(-fabsf(xx)));
      sd += dlt;
      float du = dlt * u;
      float bv[16] = {b0.x,b0.y,b0.z,b0.w, b1.x,b1.y,b1.z,b1.w,
                      b2.x,b2.y,b2.z,b2.w, b3.x,b3.y,b3.z,b3.w};
      #pragma unroll
      for (int n = 0; n < NS; ++n) h[n] = __expf(dlt * a[n]) * h[n] + du * bv[n];
    }
  }
  u32 pk[8];
  #pragma unroll
  for (int i = 0; i < 8; ++i)
    pk[i] = (u32)f2bf(h[2*i]) | ((u32)f2bf(h[2*i+1]) << 16);
  u32* outp = reinterpret_cast<u32*>(chH + ((bk * NCH + ch) * DI + t) * NS);
  *reinterpret_cast<uint4*>(outp)     = make_uint4(pk[0], pk[1], pk[2], pk[3]);
  *reinterpret_cast<uint4*>(outp + 4) = make_uint4(pk[4], pk[5], pk[6], pk[7]);
  sumd[(bk * NCH + ch) * DI + t] = sd;
}

// ------- kernel 5: carry across chunks, IN-PLACE (chH becomes h_in) ---------
__global__ __launch_bounds__(256) void k_scan2(
    u16* __restrict__ chH, const float* __restrict__ sumd,
    const float* __restrict__ Alog) {
  int t  = threadIdx.x;
  int bi = blockIdx.x;
  int bb = bi / (KK * 16);
  int k  = (bi / 16) % KK;
  int dg = bi % 16;
  int d = dg * 16 + (t >> 4);
  int n = t & 15;
  float a = -__expf(Alog[((size_t)k * DI + d) * NS + n]);
  float carry = 0.f;
  size_t bk = (size_t)bb * KK + k;
  size_t base = (bk * NCH) * DI + d;
  float Hc = bf2f(chH[base * NS + n]);
  float sd = sumd[base];
  for (int ch = 0; ch < NCH; ++ch) {
    size_t nbase = base + DI;
    float Hc2 = 0.f, sd2 = 0.f;
    if (ch + 1 < NCH) { Hc2 = bf2f(chH[nbase * NS + n]); sd2 = sumd[nbase]; }
    chH[base * NS + n] = f2bf(carry);
    carry = __expf(a * sd) * carry + Hc;
    base = nbase; Hc = Hc2; sd = sd2;
  }
}

// ------- kernel 6: scan phase 3 (re-scan with carry, emit y odd-only) -------
// Chunk-uniform streams (dts, B, C) staged in LDS; u prefetched; 6 waves/SIMD.
__global__ __launch_bounds__(256, 6) void k_scan3(
    const float* __restrict__ dts_sc, const float* __restrict__ xc,
    const float* __restrict__ xcT, const float* __restrict__ Bsb,
    const float* __restrict__ Csb, const float* __restrict__ dtw,
    const float* __restrict__ dtb, const float* __restrict__ Alog,
    const float* __restrict__ Ds, const u16* __restrict__ chH,
    u16* __restrict__ yhalf) {
  __shared__ float ldsD[CHL * RK];   // 128
  __shared__ float ldsB[CHL * NS];   // 256
  __shared__ float ldsC[CHL * NS];   // 256
  int t  = threadIdx.x;
  int bi = blockIdx.x;
  int bb = bi / (KK * NCH);
  int k  = (bi / NCH) % KK;
  int ch = bi % NCH;
  size_t bk = (size_t)bb * KK + k;
  {
    const float* dspan = dts_sc + (bk * LT + (size_t)ch * CHL) * RK;
    const float* bspan = Bsb + (bk * LT + (size_t)ch * CHL) * NS;
    const float* cspan = Csb + (bk * LT + (size_t)ch * CHL) * NS;
    if (t < CHL * RK) ldsD[t] = dspan[t];
    ldsB[t] = bspan[t];
    ldsC[t] = cspan[t];
  }
  const float* src = ((k & 1) ? xcT : xc) + (size_t)bb * LT * DI;
  int dir = (k < 2) ? 1 : -1;
  int i0  = (k < 2) ? ch * CHL : LT - 1 - ch * CHL;
  const float* wr = dtw + ((size_t)k * DI + t) * RK;
  float4 w0 = *reinterpret_cast<const float4*>(wr);
  float4 w1 = *reinterpret_cast<const float4*>(wr + 4);
  float bias = dtb[k * DI + t];
  const float* arow = Alog + ((size_t)k * DI + t) * NS;
  float a0 = -__expf(arow[0]);
  bool okf = true;
  for (int n = 1; n < NS; ++n) {
    float an = -__expf(arow[n]);
    okf = okf && (fabsf(an - (n + 1) * a0) <= 1e-3f * (n + 1) * fabsf(a0));
  }
  float h[NS];
  {
    const uint4* hp4 = reinterpret_cast<const uint4*>(chH + ((bk * NCH + ch) * DI + t) * NS);
    uint4 A = hp4[0], Bq = hp4[1];
    u32 w[8] = {A.x, A.y, A.z, A.w, Bq.x, Bq.y, Bq.z, Bq.w};
    #pragma unroll
    for (int i = 0; i < 8; ++i) {
      h[2*i]   = bf2f((u16)(w[i] & 0xFFFFu));
      h[2*i+1] = bf2f((u16)(w[i] >> 16));
    }
  }
  float dv = Ds[k * DI + t];
  float u_nxt = src[(size_t)i0 * DI + t];
  __syncthreads();
  if (okf) {
    for (int s = 0; s < CHL; ++s) {
      float u = u_nxt;
      int sn = (s + 1 < CHL) ? s + 1 : s;
      u_nxt = src[(size_t)(i0 + dir * sn) * DI + t];
      const float4* qd = reinterpret_cast<const float4*>(&ldsD[s * RK]);
      float4 q0 = qd[0], q1 = qd[1];
      const float4* bd = reinterpret_cast<const float4*>(&ldsB[s * NS]);
      float4 b0 = bd[0], b1 = bd[1], b2 = bd[2], b3 = bd[3];
      const float4* cd = reinterpret_cast<const float4*>(&ldsC[s * NS]);
      float4 c0 = cd[0], c1 = cd[1], c2 = cd[2], c3 = cd[3];
      float xx = bias + w0.x*q0.x + w0.y*q0.y + w0.z*q0.z + w0.w*q0.w
                      + w1.x*q1.x + w1.y*q1.y + w1.z*q1.z + w1.w*q1.w;
      float dlt = fmaxf(xx, 0.f) + __logf(1.f + __expf(-fabsf(xx)));
      float du = dlt * u;
      float e1 = __expf(dlt * a0);
      float bv[16] = {b0.x,b0.y,b0.z,b0.w, b1.x,b1.y,b1.z,b1.w,
                      b2.x,b2.y,b2.z,b2.w, b3.x,b3.y,b3.z,b3.w};
      float cv[16] = {c0.x,c0.y,c0.z,c0.w, c1.x,c1.y,c1.z,c1.w,
                      c2.x,c2.y,c2.z,c2.w, c3.x,c3.y,c3.z,c3.w};
      float p = e1;
      float y = 0.f;
      #pragma unroll
      for (int n = 0; n < NS; ++n) { h[n] = p * h[n] + du * bv[n]; y += h[n] * cv[n]; p *= e1; }
      y += dv * u;
      int ls = ch * CHL + s;
      int lc = lcanon(k, ls);
      if (lc & 1)
        yhalf[(bk * (LT/2) + (lc >> 1)) * DI + t] = f2bf(y);
    }
  } else {
    float a[NS];
    #pragma unroll
    for (int n = 0; n < NS; ++n) a[n] = -__expf(arow[n]);
    for (int s = 0; s < CHL; ++s) {
      float u = u_nxt;
      int sn = (s + 1 < CHL) ? s + 1 : s;
      u_nxt = src[(size_t)(i0 + dir * sn) * DI + t];
      const float4* qd = reinterpret_cast<const float4*>(&ldsD[s * RK]);
      float4 q0 = qd[0], q1 = qd[1];
      const float4* bd = reinterpret_cast<const float4*>(&ldsB[s * NS]);
      float4 b0 = bd[0], b1 = bd[1], b2 = bd[2], b3 = bd[3];
      const float4* cd = reinterpret_cast<const float4*>(&ldsC[s * NS]);
      float4 c0 = cd[0], c1 = cd[1], c2 = cd[2], c3 = cd[3];
      float xx = bias + w0.x*q0.x + w0.y*q0.y + w0.z*q0.z + w0.w*q0.w
                      + w1.x*q1.x + w1.y*q1.y + w1.z*q1.z + w1.w*q1.w;
      float dlt = fmaxf(xx, 0.f) + __logf(1.f + __expf(-fabsf(xx)));
      float du = dlt * u;
      float bv[16] = {b0.x,b0.y,b0.z,b0.w, b1.x,b1.y,b1.z,b1.w,
                      b2.x,b2.y,b2.z,b2.w, b3.x,b3.y,b3.z,b3.w};
      float cv[16] = {c0.x,c0.y,c0.z,c0.w, c1.x,c1.y,c1.z,c1.w,
                      c2.x,c2.y,c2.z,c2.w, c3.x,c3.y,c3.z,c3.w};
      float y = 0.f;
      #pragma unroll
      for (int n = 0; n < NS; ++n) { h[n] = __expf(dlt * a[n]) * h[n] + du * bv[n]; y += h[n] * cv[n]; }
      y += dv * u;
      int ls = ch * CHL + s;
      int lc = lcanon(k, ls);
      if (lc & 1)
        yhalf[(bk * (LT/2) + (lc >> 1)) * DI + t] = f2bf(y);
    }
  }
}

// ---------------- kernel 7: merge + LN + gate + out_proj (4 tok/block) ------
__global__ __launch_bounds__(256) void k_out(
    const u16* __restrict__ yhalf, const float* __restrict__ xz,
    const float* __restrict__ gam, const float* __restrict__ be,
    const float* __restrict__ opw, float* __restrict__ out) {
  __shared__ float yt[4][260];
  int t = threadIdx.x;
  int bb   = blockIdx.x / 384;
  int tile = blockIdx.x % 384;
  {
    int lane = t & 63, tok = t >> 6;
    int m = tile * 4 + tok;               // odd-token index within batch
    int lc = (m / W_) * WS2 + (m % W_) * 2 + 1;
    float yv[4];
    #pragma unroll
    for (int j = 0; j < 4; ++j) {
      int d = lane + 64 * j;
      float s = 0.f;
      #pragma unroll
      for (int k = 0; k < KK; ++k)
        s += bf2f(yhalf[(((size_t)bb * KK + k) * (LT/2) + m) * DI + d]);
      yv[j] = s;
    }
    float sum = yv[0] + yv[1] + yv[2] + yv[3];
    #pragma unroll
    for (int off = 32; off > 0; off >>= 1) sum += __shfl_xor(sum, off, 64);
    float mu = sum * (1.f / DI);
    float sq = 0.f;
    #pragma unroll
    for (int j = 0; j < 4; ++j) { float dd = yv[j] - mu; sq += dd * dd; }
    #pragma unroll
    for (int off = 32; off > 0; off >>= 1) sq += __shfl_xor(sq, off, 64);
    float rs = rsqrtf(sq * (1.f / DI) + 1e-5f);
    #pragma unroll
    for (int j = 0; j < 4; ++j) {
      int d = lane + 64 * j;
      float z = xz[((size_t)bb * LT + lc) * 512 + DI + d];
      float sz = z / (1.f + __expf(-z));
      yt[tok][d] = ((yv[j] - mu) * rs * gam[d] + be[d]) * sz;
    }
  }
  __syncthreads();
  int i = t & 3, og = t >> 2;              // token, oc in [0,64)
  const float4* yr = reinterpret_cast<const float4*>(&yt[i][0]);
  const float4* w0p = reinterpret_cast<const float4*>(opw + (size_t)og * DI);
  const float4* w1p = reinterpret_cast<const float4*>(opw + (size_t)(og + 64) * DI);
  float a0 = 0.f, a1 = 0.f;
  for (int d4 = 0; d4 < 64; ++d4) {
    float4 y4 = yr[d4];
    float4 wa = w0p[d4], wb2 = w1p[d4];
    a0 += wa.x*y4.x + wa.y*y4.y + wa.z*y4.z + wa.w*y4.w;
    a1 += wb2.x*y4.x + wb2.y*y4.y + wb2.z*y4.z + wb2.w*y4.w;
  }
  int m = tile * 4 + i;
  int hh = m / W_, ww = m % W_;
  out[((size_t)(bb * CIN + og) * HS + hh) * W_ + ww] = a0;
  out[((size_t)(bb * CIN + og + 64) * HS + hh) * W_ + ww] = a1;
}

extern "C" void kernel_launch(void* const* d_in, const int* in_sizes, int n_in,
                              void* d_out, int out_size, void* d_ws, size_t ws_size,
                              hipStream_t stream) {
  const float* rgb  = (const float*)d_in[0];
  const float* tin  = (const float*)d_in[1];
  const float* ipw  = (const float*)d_in[2];
  const float* cw   = (const float*)d_in[3];
  const float* cb   = (const float*)d_in[4];
  const float* xpw  = (const float*)d_in[5];
  const float* dtw  = (const float*)d_in[6];
  const float* dtb  = (const float*)d_in[7];
  const float* Alog = (const float*)d_in[8];
  const float* Ds   = (const float*)d_in[9];
  const float* g    = (const float*)d_in[10];
  const float* be   = (const float*)d_in[11];
  const float* opw  = (const float*)d_in[12];
  float* out = (float*)d_out;

  // f-slot layout (verified, NCH=192): end = 12,451,840 floats (~49.8 MB)
  float* ws    = (float*)d_ws;
  float* xz    = ws;                        // 3,145,728 f
  float* xc    = ws + 3145728;              // 1,572,864 f
  float* xcT   = ws + 4718592;              // 1,572,864 f
  float* dts   = ws + 6291456;              //   196,608 f
  float* Bsb   = ws + 6488064;              //   393,216 f
  float* Csb   = ws + 6881280;              //   393,216 f
  u16*   chH   = (u16*)(ws + 7274496);      // 6,291,456 bf16 = 3,145,728 f
  float* sumd  = ws + 10420224;             //   393,216 f
  u16*   yhalf = (u16*)(ws + 10813440);     // 3,145,728 bf16 = 1,572,864 f
  float* wT    = ws + 12386304;             //    65,536 f

  k_wprep  <<<64,   256, 0, stream>>>(ipw, wT);
  k_inproj <<<576,  256, 0, stream>>>(rgb, tin, wT, xz);
  k_convdbc<<<768,  256, 0, stream>>>(xz, cw, cb, xpw, xc, xcT, dts, Bsb, Csb);
  k_scan1  <<<1536, 256, 0, stream>>>(dts, xc, xcT, Bsb, dtw, dtb, Alog, chH, sumd);
  k_scan2  <<<128,  256, 0, stream>>>(chH, sumd, Alog);
  k_scan3  <<<1536, 256, 0, stream>>>(dts, xc, xcT, Bsb, Csb, dtw, dtb, Alog, Ds, chH, yhalf);
  k_out    <<<768,  256, 0, stream>>>(yhalf, xz, g, be, opw, out);
}

// Round 19
// 140.553 us; speedup vs baseline: 1.0793x; 1.0704x over previous
//
#include <hip/hip_runtime.h>

#define B_   2
#define CIN  128
#define H_   32
#define W_   48
#define HS   32
#define WS2  96
#define LT   3072
#define DI   256
#define NS   16
#define RK   8
#define KK   4
#define NCH  128
#define CHL  24   // NCH*CHL == LT

typedef unsigned int  u32;
typedef unsigned short u16;

__device__ __forceinline__ u16 f2bf(float x) {
  u32 u = __float_as_uint(x);
  return (u16)((u + 0x7FFFu + ((u >> 16) & 1u)) >> 16);
}
__device__ __forceinline__ float bf2f(u16 s) {
  return __uint_as_float((u32)s << 16);
}

// canonical token index for scan-order position ls of direction k
__device__ __forceinline__ int lcanon(int k, int ls) {
  if (k == 0) return ls;
  if (k == 1) return (ls & 31) * WS2 + (ls >> 5);
  if (k == 2) return LT - 1 - ls;
  int j = LT - 1 - ls;
  return (j & 31) * WS2 + (j >> 5);
}

// ---------------- kernel 0: weight transpose [512][128] -> [128][512] -------
__global__ __launch_bounds__(256) void k_wprep(
    const float* __restrict__ w, float* __restrict__ wT) {
  __shared__ float tile[32][33];
  int t = threadIdx.x;
  int bm = blockIdx.x & 15;    // m tile (512/32)
  int bk = blockIdx.x >> 4;    // k tile (128/32)
  int m0 = bm * 32, k0 = bk * 32;
  #pragma unroll
  for (int q = 0; q < 4; ++q) {
    int idx = q * 256 + t;
    int mi = idx >> 5, ki = idx & 31;
    tile[mi][ki] = w[(size_t)(m0 + mi) * CIN + k0 + ki];
  }
  __syncthreads();
  #pragma unroll
  for (int q = 0; q < 4; ++q) {
    int idx = q * 256 + t;
    int ki = idx >> 5, mi = idx & 31;
    wT[(size_t)(k0 + ki) * 512 + m0 + mi] = tile[mi][ki];
  }
}

// ------- kernel 1: token build + in_proj via wT, coalesced weight loads -----
// blocks [0,384): x-half (16 tok/tile); [384,576): z-half, ODD tokens only.
__global__ __launch_bounds__(256) void k_inproj(
    const float* __restrict__ rgb, const float* __restrict__ tin,
    const float* __restrict__ wT, float* __restrict__ xz) {
  __shared__ float xv[CIN][16];   // [c][tok]
  int t  = threadIdx.x;
  int bi = blockIdx.x;
  bool zh = bi >= 384;
  int bb, l0;
  if (!zh) { int r = bi;       bb = r / 192; l0 = (r % 192) * 16; }
  else     { int r = bi - 384; bb = r / 96;  l0 = (r % 96) * 32; }
  int h = l0 / WS2, w20 = l0 % WS2;
  #pragma unroll
  for (int rep = 0; rep < 8; ++rep) {
    int idx = rep * 256 + t;
    int tok = idx & 15, c = idx >> 4;
    int w2 = zh ? (w20 + 2 * tok + 1) : (w20 + tok);
    const float* src = (w2 & 1) ? tin : rgb;
    xv[c][tok] = src[((size_t)(bb * CIN + c) * HS + h) * W_ + (w2 >> 1)];
  }
  __syncthreads();
  int oc = (t & 63) * 4;          // oc within half [0,256)
  int th = t >> 6;                // token quad [0,4)
  const float4* wp = reinterpret_cast<const float4*>(wT + (zh ? 256 : 0) + oc);
  float4 A0 = {0,0,0,0}, A1 = {0,0,0,0}, A2 = {0,0,0,0}, A3 = {0,0,0,0};
  #pragma unroll 4
  for (int k = 0; k < CIN; ++k) {
    float4 w4 = wp[k * 128];      // 512 floats per k-row
    float4 x4 = *reinterpret_cast<const float4*>(&xv[k][th * 4]);
    A0.x += x4.x * w4.x; A0.y += x4.x * w4.y; A0.z += x4.x * w4.z; A0.w += x4.x * w4.w;
    A1.x += x4.y * w4.x; A1.y += x4.y * w4.y; A1.z += x4.y * w4.z; A1.w += x4.y * w4.w;
    A2.x += x4.z * w4.x; A2.y += x4.z * w4.y; A2.z += x4.z * w4.z; A2.w += x4.z * w4.w;
    A3.x += x4.w * w4.x; A3.y += x4.w * w4.y; A3.z += x4.w * w4.z; A3.w += x4.w * w4.w;
  }
  int colbase = (zh ? 256 : 0) + oc;
  #pragma unroll
  for (int j = 0; j < 4; ++j) {
    int tok = th * 4 + j;
    int l = zh ? (l0 + 2 * tok + 1) : (l0 + tok);
    float4 v = (j == 0) ? A0 : (j == 1) ? A1 : (j == 2) ? A2 : A3;
    *reinterpret_cast<float4*>(xz + ((size_t)bb * LT + l) * 512 + colbase) = v;
  }
}

// ---- kernel 2: FUSED depthwise conv+SiLU -> LDS -> x_proj/dt/B/C ----------
__global__ __launch_bounds__(256) void k_convdbc(
    const float* __restrict__ xz, const float* __restrict__ cw,
    const float* __restrict__ cbias, const float* __restrict__ xpw,
    float* __restrict__ xc, float* __restrict__ xcT,
    float* __restrict__ dts_sc, float* __restrict__ Bsb, float* __restrict__ Csb) {
  __shared__ float xv[8][260];        // [tok][d]
  __shared__ float outs2[128][9];     // B/C staging: row = k*32 + (c40-8)
  __shared__ float dts_s[KK][8][9];
  int t  = threadIdx.x;
  int bi = blockIdx.x;                // bb(2) * h(32) * q(12)
  int bb = bi / 384;
  int r  = bi % 384;
  int h  = r / 12;
  int q  = r % 12;
  int w0 = q * 8;
  int l0 = h * WS2 + w0;
  // ---- conv phase ----
  {
    float wreg[9];
    #pragma unroll
    for (int i = 0; i < 9; ++i) wreg[i] = cw[t * 9 + i];
    float bias = cbias[t];
    bool hm = (h > 0), hp = (h < HS - 1);
    const size_t rowb = ((size_t)bb * LT + h * WS2) * 512 + t;
    const size_t up = (size_t)WS2 * 512;
    float a0=0,a1=0,b0=0,b1=0,c0=0,c1=0;
    if (w0 > 0) {
      size_t o = rowb + (size_t)(w0 - 1) * 512;
      b0 = xz[o];
      if (hm) a0 = xz[o - up];
      if (hp) c0 = xz[o + up];
    }
    {
      size_t o = rowb + (size_t)w0 * 512;
      b1 = xz[o];
      if (hm) a1 = xz[o - up];
      if (hp) c1 = xz[o + up];
    }
    #pragma unroll
    for (int s = 0; s < 8; ++s) {
      int w2 = w0 + s;
      float a2 = 0, b2 = 0, c2 = 0;
      if (w2 + 1 < WS2) {
        size_t o = rowb + (size_t)(w2 + 1) * 512;
        b2 = xz[o];
        if (hm) a2 = xz[o - up];
        if (hp) c2 = xz[o + up];
      }
      float acc = bias
        + wreg[0]*a0 + wreg[1]*a1 + wreg[2]*a2
        + wreg[3]*b0 + wreg[4]*b1 + wreg[5]*b2
        + wreg[6]*c0 + wreg[7]*c1 + wreg[8]*c2;
      float sv = acc / (1.f + __expf(-acc));
      xc [((size_t)bb * LT + h * WS2 + w2) * DI + t] = sv;
      xcT[((size_t)bb * LT + w2 * 32 + h) * DI + t] = sv;   // WH-order stream
      xv[s][t] = sv;
      a0=a1; a1=a2; b0=b1; b1=b2; c0=c1; c1=c2;
    }
  }
  __syncthreads();
  // ---- x_proj phase (all 4 dirs, 160 channels) ----
  int i = t & 7, cb = t >> 3;          // token, channel base [0,32)
  float acc[5] = {0.f, 0.f, 0.f, 0.f, 0.f};
  const float4* xr  = reinterpret_cast<const float4*>(&xv[i][0]);
  const float4* wp0 = reinterpret_cast<const float4*>(xpw + (size_t)cb * DI);
  #pragma unroll 8
  for (int d4 = 0; d4 < 64; ++d4) {
    float4 x4 = xr[d4];
    #pragma unroll
    for (int j = 0; j < 5; ++j) {
      float4 w = wp0[j * 2048 + d4];   // row cb+32j
      acc[j] += w.x*x4.x + w.y*x4.y + w.z*x4.z + w.w*x4.w;
    }
  }
  #pragma unroll
  for (int j = 0; j < 5; ++j) {
    int cc  = cb + 32 * j;
    int k   = (cc * 205) >> 13;        // cc / 40
    int c40 = cc - 40 * k;
    if (c40 < RK) dts_s[k][i][c40] = acc[j];
    else          outs2[k * 32 + (c40 - RK)][i] = acc[j];
  }
  __syncthreads();
  // coalesced B/C writeout
  {
    int n = t & 15, tok = (t >> 4) & 7;
    bool isC = (t >= 128);
    int lc = l0 + tok, hh = h, w2 = w0 + tok;
    int lw = w2 * 32 + hh;
    int lsA[4] = {lc, lw, LT - 1 - lc, LT - 1 - lw};
    float* dst = isC ? Csb : Bsb;
    int off = isC ? 16 : 0;
    #pragma unroll
    for (int k = 0; k < KK; ++k)
      dst[(((size_t)bb * KK + k) * LT + lsA[k]) * NS + n] = outs2[k * 32 + off + n][tok];
  }
  // dts writeout (32B granules, scan order)
  {
    int k2 = t >> 6, tok2 = (t >> 3) & 7, rr = t & 7;
    int lc2 = l0 + tok2;
    int lw2 = (w0 + tok2) * 32 + h;
    int ls2 = (k2 == 0) ? lc2 : (k2 == 1) ? lw2 : (k2 == 2) ? (LT - 1 - lc2) : (LT - 1 - lw2);
    dts_sc[(((size_t)bb * KK + k2) * LT + ls2) * RK + rr] = dts_s[k2][tok2][rr];
  }
}

// ---------------- kernel 4: scan phase 1 (per-chunk local state) ------------
// Chunk-uniform streams (dts, B) staged in LDS; u prefetched; 6 waves/SIMD.
__global__ __launch_bounds__(256, 6) void k_scan1(
    const float* __restrict__ dts_sc, const float* __restrict__ xc,
    const float* __restrict__ xcT, const float* __restrict__ Bsb,
    const float* __restrict__ dtw, const float* __restrict__ dtb,
    const float* __restrict__ Alog, u16* __restrict__ chH,
    float* __restrict__ sumd) {
  __shared__ float ldsD[CHL * RK];   // 192 floats
  __shared__ float ldsB[CHL * NS];   // 384 floats
  int t  = threadIdx.x;
  int bi = blockIdx.x;
  int bb = bi / (KK * NCH);
  int k  = (bi / NCH) % KK;
  int ch = bi % NCH;
  size_t bk = (size_t)bb * KK + k;
  {
    const float* dspan = dts_sc + (bk * LT + (size_t)ch * CHL) * RK;  // 192 f
    const float* bspan = Bsb + (bk * LT + (size_t)ch * CHL) * NS;     // 384 f
    if (t < CHL * RK) ldsD[t] = dspan[t];
    for (int i = t; i < CHL * NS; i += 256) ldsB[i] = bspan[i];
  }
  const float* src = ((k & 1) ? xcT : xc) + (size_t)bb * LT * DI;
  int dir = (k < 2) ? 1 : -1;
  int i0  = (k < 2) ? ch * CHL : LT - 1 - ch * CHL;
  const float* wr = dtw + ((size_t)k * DI + t) * RK;
  float4 w0 = *reinterpret_cast<const float4*>(wr);
  float4 w1 = *reinterpret_cast<const float4*>(wr + 4);
  float bias = dtb[k * DI + t];
  const float* arow = Alog + ((size_t)k * DI + t) * NS;
  float a0 = -__expf(arow[0]);
  bool okf = true;
  for (int n = 1; n < NS; ++n) {
    float an = -__expf(arow[n]);
    okf = okf && (fabsf(an - (n + 1) * a0) <= 1e-3f * (n + 1) * fabsf(a0));
  }
  float h[NS];
  #pragma unroll
  for (int n = 0; n < NS; ++n) h[n] = 0.f;
  float sd = 0.f;
  float u_nxt = src[(size_t)i0 * DI + t];
  __syncthreads();
  if (okf) {
    for (int s = 0; s < CHL; ++s) {
      float u = u_nxt;
      int sn = (s + 1 < CHL) ? s + 1 : s;
      u_nxt = src[(size_t)(i0 + dir * sn) * DI + t];
      const float4* qd = reinterpret_cast<const float4*>(&ldsD[s * RK]);
      float4 q0 = qd[0], q1 = qd[1];
      const float4* bd = reinterpret_cast<const float4*>(&ldsB[s * NS]);
      float4 b0 = bd[0], b1 = bd[1], b2 = bd[2], b3 = bd[3];
      float xx = bias + w0.x*q0.x + w0.y*q0.y + w0.z*q0.z + w0.w*q0.w
                      + w1.x*q1.x + w1.y*q1.y + w1.z*q1.z + w1.w*q1.w;
      float dlt = fmaxf(xx, 0.f) + __logf(1.f + __expf(-fabsf(xx)));
      sd += dlt;
      float du = dlt * u;
      float e1 = __expf(dlt * a0);
      float bv[16] = {b0.x,b0.y,b0.z,b0.w, b1.x,b1.y,b1.z,b1.w,
                      b2.x,b2.y,b2.z,b2.w, b3.x,b3.y,b3.z,b3.w};
      float p = e1;
      #pragma unroll
      for (int n = 0; n < NS; ++n) { h[n] = p * h[n] + du * bv[n]; p *= e1; }
    }
  } else {
    float a[NS];
    #pragma unroll
    for (int n = 0; n < NS; ++n) a[n] = -__expf(arow[n]);
    for (int s = 0; s < CHL; ++s) {
      float u = u_nxt;
      int sn = (s + 1 < CHL) ? s + 1 : s;
      u_nxt = src[(size_t)(i0 + dir * sn) * DI + t];
      const float4* qd = reinterpret_cast<const float4*>(&ldsD[s * RK]);
      float4 q0 = qd[0], q1 = qd[1];
      const float4* bd = reinterpret_cast<const float4*>(&ldsB[s * NS]);
      float4 b0 = bd[0], b1 = bd[1], b2 = bd[2], b3 = bd[3];
      float xx = bias + w0.x*q0.x + w0.y*q0.y + w0.z*q0.z + w0.w*q0.w
                      + w1.x*q1.x + w1.y*q1.y + w1.z*q1.z + w1.w*q1.w;
      float dlt = fmaxf(xx, 0.f) + __logf(1.f + __expf(-fabsf(xx)));
      sd += dlt;
      float du = dlt * u;
      float bv[16] = {b0.x,b0.y,b0.z,b0.w, b1.x,b1.y,b1.z,b1.w,
                      b2.x,b2.y,b2.z,b2.w, b3.x,b3.y,b3.z,b3.w};
      #pragma unroll
      for (int n = 0; n < NS; ++n) h[n] = __expf(dlt * a[n]) * h[n] + du * bv[n];
    }
  }
  u32 pk[8];
  #pragma unroll
  for (int i = 0; i < 8; ++i)
    pk[i] = (u32)f2bf(h[2*i]) | ((u32)f2bf(h[2*i+1]) << 16);
  u32* outp = reinterpret_cast<u32*>(chH + ((bk * NCH + ch) * DI + t) * NS);
  *reinterpret_cast<uint4*>(outp)     = make_uint4(pk[0], pk[1], pk[2], pk[3]);
  *reinterpret_cast<uint4*>(outp + 4) = make_uint4(pk[4], pk[5], pk[6], pk[7]);
  sumd[(bk * NCH + ch) * DI + t] = sd;
}

// ------- kernel 5: carry across chunks, IN-PLACE (chH becomes h_in) ---------
__global__ __launch_bounds__(256) void k_scan2(
    u16* __restrict__ chH, const float* __restrict__ sumd,
    const float* __restrict__ Alog) {
  int t  = threadIdx.x;
  int bi = blockIdx.x;
  int bb = bi / (KK * 16);
  int k  = (bi / 16) % KK;
  int dg = bi % 16;
  int d = dg * 16 + (t >> 4);
  int n = t & 15;
  float a = -__expf(Alog[((size_t)k * DI + d) * NS + n]);
  float carry = 0.f;
  size_t bk = (size_t)bb * KK + k;
  size_t base = (bk * NCH) * DI + d;
  float Hc = bf2f(chH[base * NS + n]);
  float sd = sumd[base];
  for (int ch = 0; ch < NCH; ++ch) {
    size_t nbase = base + DI;
    float Hc2 = 0.f, sd2 = 0.f;
    if (ch + 1 < NCH) { Hc2 = bf2f(chH[nbase * NS + n]); sd2 = sumd[nbase]; }
    chH[base * NS + n] = f2bf(carry);
    carry = __expf(a * sd) * carry + Hc;
    base = nbase; Hc = Hc2; sd = sd2;
  }
}

// ------- kernel 6: scan phase 3 (re-scan with carry, emit y odd-only) -------
// Chunk-uniform streams (dts, B, C) staged in LDS; u prefetched; 6 waves/SIMD.
__global__ __launch_bounds__(256, 6) void k_scan3(
    const float* __restrict__ dts_sc, const float* __restrict__ xc,
    const float* __restrict__ xcT, const float* __restrict__ Bsb,
    const float* __restrict__ Csb, const float* __restrict__ dtw,
    const float* __restrict__ dtb, const float* __restrict__ Alog,
    const float* __restrict__ Ds, const u16* __restrict__ chH,
    u16* __restrict__ yhalf) {
  __shared__ float ldsD[CHL * RK];   // 192
  __shared__ float ldsB[CHL * NS];   // 384
  __shared__ float ldsC[CHL * NS];   // 384
  int t  = threadIdx.x;
  int bi = blockIdx.x;
  int bb = bi / (KK * NCH);
  int k  = (bi / NCH) % KK;
  int ch = bi % NCH;
  size_t bk = (size_t)bb * KK + k;
  {
    const float* dspan = dts_sc + (bk * LT + (size_t)ch * CHL) * RK;
    const float* bspan = Bsb + (bk * LT + (size_t)ch * CHL) * NS;
    const float* cspan = Csb + (bk * LT + (size_t)ch * CHL) * NS;
    if (t < CHL * RK) ldsD[t] = dspan[t];
    for (int i = t; i < CHL * NS; i += 256) {
      ldsB[i] = bspan[i];
      ldsC[i] = cspan[i];
    }
  }
  const float* src = ((k & 1) ? xcT : xc) + (size_t)bb * LT * DI;
  int dir = (k < 2) ? 1 : -1;
  int i0  = (k < 2) ? ch * CHL : LT - 1 - ch * CHL;
  const float* wr = dtw + ((size_t)k * DI + t) * RK;
  float4 w0 = *reinterpret_cast<const float4*>(wr);
  float4 w1 = *reinterpret_cast<const float4*>(wr + 4);
  float bias = dtb[k * DI + t];
  const float* arow = Alog + ((size_t)k * DI + t) * NS;
  float a0 = -__expf(arow[0]);
  bool okf = true;
  for (int n = 1; n < NS; ++n) {
    float an = -__expf(arow[n]);
    okf = okf && (fabsf(an - (n + 1) * a0) <= 1e-3f * (n + 1) * fabsf(a0));
  }
  float h[NS];
  {
    const uint4* hp4 = reinterpret_cast<const uint4*>(chH + ((bk * NCH + ch) * DI + t) * NS);
    uint4 A = hp4[0], Bq = hp4[1];
    u32 w[8] = {A.x, A.y, A.z, A.w, Bq.x, Bq.y, Bq.z, Bq.w};
    #pragma unroll
    for (int i = 0; i < 8; ++i) {
      h[2*i]   = bf2f((u16)(w[i] & 0xFFFFu));
      h[2*i+1] = bf2f((u16)(w[i] >> 16));
    }
  }
  float dv = Ds[k * DI + t];
  float u_nxt = src[(size_t)i0 * DI + t];
  __syncthreads();
  if (okf) {
    for (int s = 0; s < CHL; ++s) {
      float u = u_nxt;
      int sn = (s + 1 < CHL) ? s + 1 : s;
      u_nxt = src[(size_t)(i0 + dir * sn) * DI + t];
      const float4* qd = reinterpret_cast<const float4*>(&ldsD[s * RK]);
      float4 q0 = qd[0], q1 = qd[1];
      const float4* bd = reinterpret_cast<const float4*>(&ldsB[s * NS]);
      float4 b0 = bd[0], b1 = bd[1], b2 = bd[2], b3 = bd[3];
      const float4* cd = reinterpret_cast<const float4*>(&ldsC[s * NS]);
      float4 c0 = cd[0], c1 = cd[1], c2 = cd[2], c3 = cd[3];
      float xx = bias + w0.x*q0.x + w0.y*q0.y + w0.z*q0.z + w0.w*q0.w
                      + w1.x*q1.x + w1.y*q1.y + w1.z*q1.z + w1.w*q1.w;
      float dlt = fmaxf(xx, 0.f) + __logf(1.f + __expf(-fabsf(xx)));
      float du = dlt * u;
      float e1 = __expf(dlt * a0);
      float bv[16] = {b0.x,b0.y,b0.z,b0.w, b1.x,b1.y,b1.z,b1.w,
                      b2.x,b2.y,b2.z,b2.w, b3.x,b3.y,b3.z,b3.w};
      float cv[16] = {c0.x,c0.y,c0.z,c0.w, c1.x,c1.y,c1.z,c1.w,
                      c2.x,c2.y,c2.z,c2.w, c3.x,c3.y,c3.z,c3.w};
      float p = e1;
      float y = 0.f;
      #pragma unroll
      for (int n = 0; n < NS; ++n) { h[n] = p * h[n] + du * bv[n]; y += h[n] * cv[n]; p *= e1; }
      y += dv * u;
      int ls = ch * CHL + s;
      int lc = lcanon(k, ls);
      if (lc & 1)
        yhalf[(bk * (LT/2) + (lc >> 1)) * DI + t] = f2bf(y);
    }
  } else {
    float a[NS];
    #pragma unroll
    for (int n = 0; n < NS; ++n) a[n] = -__expf(arow[n]);
    for (int s = 0; s < CHL; ++s) {
      float u = u_nxt;
      int sn = (s + 1 < CHL) ? s + 1 : s;
      u_nxt = src[(size_t)(i0 + dir * sn) * DI + t];
      const float4* qd = reinterpret_cast<const float4*>(&ldsD[s * RK]);
      float4 q0 = qd[0], q1 = qd[1];
      const float4* bd = reinterpret_cast<const float4*>(&ldsB[s * NS]);
      float4 b0 = bd[0], b1 = bd[1], b2 = bd[2], b3 = bd[3];
      const float4* cd = reinterpret_cast<const float4*>(&ldsC[s * NS]);
      float4 c0 = cd[0], c1 = cd[1], c2 = cd[2], c3 = cd[3];
      float xx = bias + w0.x*q0.x + w0.y*q0.y + w0.z*q0.z + w0.w*q0.w
                      + w1.x*q1.x + w1.y*q1.y + w1.z*q1.z + w1.w*q1.w;
      float dlt = fmaxf(xx, 0.f) + __logf(1.f + __expf(-fabsf(xx)));
      float du = dlt * u;
      float bv[16] = {b0.x,b0.y,b0.z,b0.w, b1.x,b1.y,b1.z,b1.w,
                      b2.x,b2.y,b2.z,b2.w, b3.x,b3.y,b3.z,b3.w};
      float cv[16] = {c0.x,c0.y,c0.z,c0.w, c1.x,c1.y,c1.z,c1.w,
                      c2.x,c2.y,c2.z,c2.w, c3.x,c3.y,c3.z,c3.w};
      float y = 0.f;
      #pragma unroll
      for (int n = 0; n < NS; ++n) { h[n] = __expf(dlt * a[n]) * h[n] + du * bv[n]; y += h[n] * cv[n]; }
      y += dv * u;
      int ls = ch * CHL + s;
      int lc = lcanon(k, ls);
      if (lc & 1)
        yhalf[(bk * (LT/2) + (lc >> 1)) * DI + t] = f2bf(y);
    }
  }
}

// ---------------- kernel 7: merge + LN + gate + out_proj (4 tok/block) ------
__global__ __launch_bounds__(256) void k_out(
    const u16* __restrict__ yhalf, const float* __restrict__ xz,
    const float* __restrict__ gam, const float* __restrict__ be,
    const float* __restrict__ opw, float* __restrict__ out) {
  __shared__ float yt[4][260];
  int t = threadIdx.x;
  int bb   = blockIdx.x / 384;
  int tile = blockIdx.x % 384;
  {
    int lane = t & 63, tok = t >> 6;
    int m = tile * 4 + tok;               // odd-token index within batch
    int lc = (m / W_) * WS2 + (m % W_) * 2 + 1;
    float yv[4];
    #pragma unroll
    for (int j = 0; j < 4; ++j) {
      int d = lane + 64 * j;
      float s = 0.f;
      #pragma unroll
      for (int k = 0; k < KK; ++k)
        s += bf2f(yhalf[(((size_t)bb * KK + k) * (LT/2) + m) * DI + d]);
      yv[j] = s;
    }
    float sum = yv[0] + yv[1] + yv[2] + yv[3];
    #pragma unroll
    for (int off = 32; off > 0; off >>= 1) sum += __shfl_xor(sum, off, 64);
    float mu = sum * (1.f / DI);
    float sq = 0.f;
    #pragma unroll
    for (int j = 0; j < 4; ++j) { float dd = yv[j] - mu; sq += dd * dd; }
    #pragma unroll
    for (int off = 32; off > 0; off >>= 1) sq += __shfl_xor(sq, off, 64);
    float rs = rsqrtf(sq * (1.f / DI) + 1e-5f);
    #pragma unroll
    for (int j = 0; j < 4; ++j) {
      int d = lane + 64 * j;
      float z = xz[((size_t)bb * LT + lc) * 512 + DI + d];
      float sz = z / (1.f + __expf(-z));
      yt[tok][d] = ((yv[j] - mu) * rs * gam[d] + be[d]) * sz;
    }
  }
  __syncthreads();
  int i = t & 3, og = t >> 2;              // token, oc in [0,64)
  const float4* yr = reinterpret_cast<const float4*>(&yt[i][0]);
  const float4* w0p = reinterpret_cast<const float4*>(opw + (size_t)og * DI);
  const float4* w1p = reinterpret_cast<const float4*>(opw + (size_t)(og + 64) * DI);
  float a0 = 0.f, a1 = 0.f;
  for (int d4 = 0; d4 < 64; ++d4) {
    float4 y4 = yr[d4];
    float4 wa = w0p[d4], wb2 = w1p[d4];
    a0 += wa.x*y4.x + wa.y*y4.y + wa.z*y4.z + wa.w*y4.w;
    a1 += wb2.x*y4.x + wb2.y*y4.y + wb2.z*y4.z + wb2.w*y4.w;
  }
  int m = tile * 4 + i;
  int hh = m / W_, ww = m % W_;
  out[((size_t)(bb * CIN + og) * HS + hh) * W_ + ww] = a0;
  out[((size_t)(bb * CIN + og + 64) * HS + hh) * W_ + ww] = a1;
}

extern "C" void kernel_launch(void* const* d_in, const int* in_sizes, int n_in,
                              void* d_out, int out_size, void* d_ws, size_t ws_size,
                              hipStream_t stream) {
  const float* rgb  = (const float*)d_in[0];
  const float* tin  = (const float*)d_in[1];
  const float* ipw  = (const float*)d_in[2];
  const float* cw   = (const float*)d_in[3];
  const float* cb   = (const float*)d_in[4];
  const float* xpw  = (const float*)d_in[5];
  const float* dtw  = (const float*)d_in[6];
  const float* dtb  = (const float*)d_in[7];
  const float* Alog = (const float*)d_in[8];
  const float* Ds   = (const float*)d_in[9];
  const float* g    = (const float*)d_in[10];
  const float* be   = (const float*)d_in[11];
  const float* opw  = (const float*)d_in[12];
  float* out = (float*)d_out;

  float* ws    = (float*)d_ws;
  float* xz    = ws;                  // B*L*512                 = 3,145,728 f
  float* xc    = xz    + 3145728;     // B*L*256                 = 1,572,864 f
  float* xcT   = xc    + 1572864;     // B*L*256                 = 1,572,864 f
  float* dts   = xcT   + 1572864;     // B*K*L*8                 =   196,608 f
  float* Bsb   = dts   + 196608;      // B*K*L*16                =   393,216 f
  float* Csb   = Bsb   + 393216;      //                         =   393,216 f
  u16*   chH   = (u16*)(Csb + 393216);// B*K*NCH*256*16 bf16     = 2,097,152 f-slots
  float* sumd  = Csb   + 393216 + 2097152;  // B*K*NCH*256       =   262,144 f
  u16*   yhalf = (u16*)(sumd + 262144);     // B*K*(L/2)*256 bf16= 1,572,864 f-slots
  float* wT    = sumd  + 262144 + 1572864;  // 128*512           =    65,536 f

  k_wprep  <<<64,   256, 0, stream>>>(ipw, wT);
  k_inproj <<<576,  256, 0, stream>>>(rgb, tin, wT, xz);
  k_convdbc<<<768,  256, 0, stream>>>(xz, cw, cb, xpw, xc, xcT, dts, Bsb, Csb);
  k_scan1  <<<1024, 256, 0, stream>>>(dts, xc, xcT, Bsb, dtw, dtb, Alog, chH, sumd);
  k_scan2  <<<128,  256, 0, stream>>>(chH, sumd, Alog);
  k_scan3  <<<1024, 256, 0, stream>>>(dts, xc, xcT, Bsb, Csb, dtw, dtb, Alog, Ds, chH, yhalf);
  k_out    <<<768,  256, 0, stream>>>(yhalf, xz, g, be, opw, out);
}